// Round 6
// baseline (135.971 us; speedup 1.0000x reference)
//
#include <hip/hip_runtime.h>
#include <hip/hip_bf16.h>

#define BATCH 16
#define HW 50176          // 224*224
#define HID 256
#define K 64

// output layout (floats): transformed [0, 2408448) | m [2408448, 53788672) | palette [53788672, +3072)
#define OUT_T_OFF 0
#define OUT_M_OFF 2408448
#define OUT_P_OFF 53788672

// workspace layout (floats): den [0,1024) | num [1024,4096) | w1p float4 [4096,5120) | w2b bf16 @ float-offset 5120 (32KB)
#define WS_DEN 0
#define WS_NUM 1024
#define WS_W1P 4096
#define WS_W2B 5120

typedef short bf16x8 __attribute__((ext_vector_type(8)));
typedef float f32x4  __attribute__((ext_vector_type(4)));

static __device__ __forceinline__ short f2bf(float x) {
    union { __hip_bfloat16 h; short s; } u;
    u.h = __float2bfloat16(x);
    return u.s;
}

// Prep (8 blocks): block 0 zeroes den/num and packs W1+b1; all blocks convert W2 slice to bf16.
__global__ __launch_bounds__(256) void colorcnn_prep(
    const float* __restrict__ W1, const float* __restrict__ b1,
    const float* __restrict__ W2, float* __restrict__ wsf,
    float4* __restrict__ w1p, ushort* __restrict__ w2b)
{
    const int t = threadIdx.x;
    if (blockIdx.x == 0) {
#pragma unroll
        for (int q = 0; q < 16; ++q) wsf[q * 256 + t] = 0.f;   // den[1024] + num[3072]
        w1p[t] = make_float4(W1[3 * t], W1[3 * t + 1], W1[3 * t + 2], b1[t]);
    }
#pragma unroll
    for (int q = 0; q < 8; ++q) {
        const int i = (blockIdx.x * 8 + q) * 256 + t;
        w2b[i] = (ushort)f2bf(W2[i]);
    }
}

// Kernel A: per-pixel MLP via MFMA + softmax (no max-subtract; logits bounded) + m store
// + fused den/num reduction. Block = 256 px; 4 waves x 64 px each.
__global__ __launch_bounds__(256) void colorcnn_mlp_softmax(
    const float* __restrict__ img, const float4* __restrict__ w1p,
    const ushort* __restrict__ w2b, float* __restrict__ m_out,
    float* __restrict__ den_ws, float* __restrict__ num_ws)
{
    __shared__ int4 lds[2304];       // [0,2048): w2b swizzled; [2048,2304): w1p swizzled
    __shared__ float sred[4][256];   // per-wave den/num partials

    const int t = threadIdx.x;
    // stage w2b: 2048 16B units; unit s of row n stored at n*32 + (s ^ (n&7))
    const int4* w2b16 = (const int4*)w2b;
#pragma unroll
    for (int q = 0; q < 8; ++q) {
        const int i = t + q * 256;
        const int n = i >> 5, s = i & 31;
        lds[n * 32 + (s ^ (n & 7))] = w2b16[i];
    }
    // stage w1p: unit hid stored at 2048 + (hid ^ ((hid>>3)&3))
    lds[2048 + (t ^ ((t >> 3) & 3))] = ((const int4*)w1p)[t];
    __syncthreads();

    const int b    = blockIdx.y;
    const int pb   = blockIdx.x * 256;
    const int w    = t >> 6;
    const int lane = t & 63;
    const int l15  = lane & 15;
    const int lg   = lane >> 4;
    const int pwb  = pb + w * 64;

    const float* ip = img + (size_t)b * 3 * HW;

    // rgb for 4 pixel-groups (A-frag rows: px = pwb + s*16 + l15)
    float rr[4], gg[4], uu[4];
#pragma unroll
    for (int s = 0; s < 4; ++s) {
        const int px = pwb + s * 16 + l15;
        rr[s] = ip[px]; gg[s] = ip[HW + px]; uu[s] = ip[2 * HW + px];
    }

    f32x4 acc[4][4];
#pragma unroll
    for (int s = 0; s < 4; ++s)
#pragma unroll
        for (int ni = 0; ni < 4; ++ni)
            acc[s][ni] = (f32x4){0.f, 0.f, 0.f, 0.f};

#pragma unroll
    for (int c = 0; c < 8; ++c) {
        // A fragments: lane holds h[px][hid], hid = c*32 + lg*8 + j, for 4 px-groups
        bf16x8 a0, a1, a2, a3;
#pragma unroll
        for (int j = 0; j < 8; ++j) {
            const int hid = c * 32 + lg * 8 + j;
            const float4 wv = *(const float4*)&lds[2048 + (hid ^ lg)];
            float t0 = fmaf(rr[0], wv.x, fmaf(gg[0], wv.y, fmaf(uu[0], wv.z, wv.w)));
            float t1 = fmaf(rr[1], wv.x, fmaf(gg[1], wv.y, fmaf(uu[1], wv.z, wv.w)));
            float t2 = fmaf(rr[2], wv.x, fmaf(gg[2], wv.y, fmaf(uu[2], wv.z, wv.w)));
            float t3 = fmaf(rr[3], wv.x, fmaf(gg[3], wv.y, fmaf(uu[3], wv.z, wv.w)));
            a0[j] = f2bf(fmaxf(t0, 0.f));
            a1[j] = f2bf(fmaxf(t1, 0.f));
            a2[j] = f2bf(fmaxf(t2, 0.f));
            a3[j] = f2bf(fmaxf(t3, 0.f));
        }
        // B fragments from LDS (swizzled) + 16 MFMA
#pragma unroll
        for (int ni = 0; ni < 4; ++ni) {
            const int n = ni * 16 + l15;
            const bf16x8 bf = *(const bf16x8*)&lds[n * 32 + (((c * 4 + lg) ^ (n & 7)))];
            acc[0][ni] = __builtin_amdgcn_mfma_f32_16x16x32_bf16(a0, bf, acc[0][ni], 0, 0, 0);
            acc[1][ni] = __builtin_amdgcn_mfma_f32_16x16x32_bf16(a1, bf, acc[1][ni], 0, 0, 0);
            acc[2][ni] = __builtin_amdgcn_mfma_f32_16x16x32_bf16(a2, bf, acc[2][ni], 0, 0, 0);
            acc[3][ni] = __builtin_amdgcn_mfma_f32_16x16x32_bf16(a3, bf, acc[3][ni], 0, 0, 0);
        }
    }

    // Softmax over n=64 per pixel, WITHOUT max-subtraction (logits bounded ~|1.5|, fp32 exp safe).
    // C layout: col(n)=ni*16+l15, row(px within group s)=lg*4+reg. Reduce over ni in-lane + l15 xor.
#pragma unroll
    for (int s = 0; s < 4; ++s) {
#pragma unroll
        for (int reg = 0; reg < 4; ++reg) {
            float v0 = __expf(acc[s][0][reg]);
            float v1 = __expf(acc[s][1][reg]);
            float v2 = __expf(acc[s][2][reg]);
            float v3 = __expf(acc[s][3][reg]);
            float sm = (v0 + v1) + (v2 + v3);
            sm += __shfl_xor(sm, 1);
            sm += __shfl_xor(sm, 2);
            sm += __shfl_xor(sm, 4);
            sm += __shfl_xor(sm, 8);
            const float inv = 1.f / sm;
            acc[s][0][reg] = v0 * inv; acc[s][1][reg] = v1 * inv;
            acc[s][2][reg] = v2 * inv; acc[s][3][reg] = v3 * inv;
        }
    }

    // Store m: per (s,ni) the 4 regs are 4 consecutive px -> dwordx4.
    float* mo = m_out + (size_t)b * K * HW + pwb;
#pragma unroll
    for (int s = 0; s < 4; ++s)
#pragma unroll
        for (int ni = 0; ni < 4; ++ni) {
            const int n = ni * 16 + l15;
            *(f32x4*)&mo[(size_t)n * HW + s * 16 + lg * 4] = acc[s][ni];
        }

    // ---- Fused den/num reduction ----
    // Lane's pixels: px = pwb + s*16 + lg*4 + reg. Broadcast f32x4 img loads.
    f32x4 rC[4], gC[4], uC[4];
#pragma unroll
    for (int s = 0; s < 4; ++s) {
        const int pxb = pwb + s * 16 + lg * 4;
        rC[s] = *(const f32x4*)&ip[pxb];
        gC[s] = *(const f32x4*)&ip[HW + pxb];
        uC[s] = *(const f32x4*)&ip[2 * HW + pxb];
    }
    float red[16];   // [q*4+ni], q: 0=den 1=numR 2=numG 3=numB
#pragma unroll
    for (int ni = 0; ni < 4; ++ni) {
        float d = 0.f, nr = 0.f, ng = 0.f, nb = 0.f;
#pragma unroll
        for (int s = 0; s < 4; ++s) {
#pragma unroll
            for (int reg = 0; reg < 4; ++reg) {
                const float mv = acc[s][ni][reg];
                d += mv;
                nr = fmaf(rC[s][reg], mv, nr);
                ng = fmaf(gC[s][reg], mv, ng);
                nb = fmaf(uC[s][reg], mv, nb);
            }
        }
        red[ni] = d; red[4 + ni] = nr; red[8 + ni] = ng; red[12 + ni] = nb;
    }
    // Reduce across the 4 lane-groups (lanes sharing l15): xor 16, 32.
#pragma unroll
    for (int i = 0; i < 16; ++i) {
        red[i] += __shfl_xor(red[i], 16);
        red[i] += __shfl_xor(red[i], 32);
    }
    if (lg == 0) {
#pragma unroll
        for (int ni = 0; ni < 4; ++ni) {
            const int n = ni * 16 + l15;
            sred[w][n]       = red[ni];
            sred[w][64 + n]  = red[4 + ni];
            sred[w][128 + n] = red[8 + ni];
            sred[w][192 + n] = red[12 + ni];
        }
    }
    __syncthreads();
    {
        const int q = t >> 6, n = t & 63;
        const float v = sred[0][t] + sred[1][t] + sred[2][t] + sred[3][t];
        if (q == 0) atomicAdd(&den_ws[b * K + n], v);
        else        atomicAdd(&num_ws[(b * 3 + (q - 1)) * K + n], v);
    }
}

// Kernel P: palette[b,c,k] = num/(den+eps)
__global__ __launch_bounds__(256) void colorcnn_palette(
    const float* __restrict__ den_ws, const float* __restrict__ num_ws,
    float* __restrict__ pal_out)
{
    const int i = blockIdx.x * 256 + threadIdx.x;
    if (i >= BATCH * K) return;
    const int b = i >> 6;
    const int k = i & 63;
    const float dv = den_ws[i] + 1e-8f;
#pragma unroll
    for (int c = 0; c < 3; ++c)
        pal_out[b * 3 * K + c * K + k] = num_ws[(b * 3 + c) * K + k] / dv;
}

// Kernel C: transformed[b,c,p] = sum_k m[b,k,p] * palette[b,c,k]. 4 px/thread, f32x4.
__global__ __launch_bounds__(256) void colorcnn_reconstruct(
    const float* __restrict__ m, const float* __restrict__ pal,
    float* __restrict__ t_out)
{
    __shared__ float pl[192];
    const int b = blockIdx.x / 49;
    const int p = (blockIdx.x % 49) * 1024 + threadIdx.x * 4;

    if (threadIdx.x < 192) pl[threadIdx.x] = pal[b * 3 * K + threadIdx.x];
    __syncthreads();

    const float* mp = m + (size_t)b * K * HW + p;
    f32x4 ar = {0.f, 0.f, 0.f, 0.f}, ag = ar, ab = ar;
#pragma unroll
    for (int k = 0; k < K; ++k) {
        const f32x4 mv = *(const f32x4*)&mp[(size_t)k * HW];
        const float pr = pl[k], pg = pl[K + k], pu = pl[2 * K + k];
#pragma unroll
        for (int j = 0; j < 4; ++j) {
            ar[j] = fmaf(mv[j], pr, ar[j]);
            ag[j] = fmaf(mv[j], pg, ag[j]);
            ab[j] = fmaf(mv[j], pu, ab[j]);
        }
    }
    float* to = t_out + (size_t)b * 3 * HW + p;
    *(f32x4*)&to[0]      = ar;
    *(f32x4*)&to[HW]     = ag;
    *(f32x4*)&to[2 * HW] = ab;
}

extern "C" void kernel_launch(void* const* d_in, const int* in_sizes, int n_in,
                              void* d_out, int out_size, void* d_ws, size_t ws_size,
                              hipStream_t stream) {
    const float* img = (const float*)d_in[0];
    const float* W1  = (const float*)d_in[1];
    const float* b1  = (const float*)d_in[2];
    const float* W2  = (const float*)d_in[3];

    float* out   = (float*)d_out;
    float* t_out = out + OUT_T_OFF;
    float* m_out = out + OUT_M_OFF;
    float* p_out = out + OUT_P_OFF;

    float*  wsf    = (float*)d_ws;
    float*  den_ws = wsf + WS_DEN;
    float*  num_ws = wsf + WS_NUM;
    float4* w1p    = (float4*)(wsf + WS_W1P);
    ushort* w2b    = (ushort*)(wsf + WS_W2B);

    colorcnn_prep<<<8, 256, 0, stream>>>(W1, b1, W2, wsf, w1p, w2b);
    colorcnn_mlp_softmax<<<dim3(HW / 256, BATCH), 256, 0, stream>>>(img, w1p, w2b, m_out, den_ws, num_ws);
    colorcnn_palette<<<4, 256, 0, stream>>>(den_ws, num_ws, p_out);
    colorcnn_reconstruct<<<BATCH * 49, 256, 0, stream>>>(m_out, p_out, t_out);
}

// Round 7
// 125.008 us; speedup vs baseline: 1.0877x; 1.0877x over previous
//
#include <hip/hip_runtime.h>
#include <hip/hip_bf16.h>

#define BATCH 16
#define HW 50176          // 224*224
#define HID 256
#define K 64

// output layout (floats): transformed [0, 2408448) | m [2408448, 53788672) | palette [53788672, +3072)
#define OUT_T_OFF 0
#define OUT_M_OFF 2408448
#define OUT_P_OFF 53788672

// workspace layout (floats): den [0,1024) | num [1024,4096) | w1p float4 [4096,5120) | w2b bf16 @ float-offset 5120 (32KB)
#define WS_DEN 0
#define WS_NUM 1024
#define WS_W1P 4096
#define WS_W2B 5120

typedef short bf16x8 __attribute__((ext_vector_type(8)));
typedef float f32x4  __attribute__((ext_vector_type(4)));

static __device__ __forceinline__ short f2bf(float x) {
    union { __hip_bfloat16 h; short s; } u;
    u.h = __float2bfloat16(x);
    return u.s;
}

// Prep (8 blocks): block 0 zeroes den/num and packs W1+b1; all blocks convert W2 slice to bf16.
__global__ __launch_bounds__(256) void colorcnn_prep(
    const float* __restrict__ W1, const float* __restrict__ b1,
    const float* __restrict__ W2, float* __restrict__ wsf,
    float4* __restrict__ w1p, ushort* __restrict__ w2b)
{
    const int t = threadIdx.x;
    if (blockIdx.x == 0) {
#pragma unroll
        for (int q = 0; q < 16; ++q) wsf[q * 256 + t] = 0.f;   // den[1024] + num[3072]
        w1p[t] = make_float4(W1[3 * t], W1[3 * t + 1], W1[3 * t + 2], b1[t]);
    }
#pragma unroll
    for (int q = 0; q < 8; ++q) {
        const int i = (blockIdx.x * 8 + q) * 256 + t;
        w2b[i] = (ushort)f2bf(W2[i]);
    }
}

// Kernel A: per-pixel MLP via MFMA + softmax (no max-subtract; logits bounded) + fused den/num
// reduction + m store (stores issued LAST so the barrier never waits on them).
// Block = 256 px; 4 waves x 64 px each.
__global__ __launch_bounds__(256) void colorcnn_mlp_softmax(
    const float* __restrict__ img, const float4* __restrict__ w1p,
    const ushort* __restrict__ w2b, float* __restrict__ m_out,
    float* __restrict__ den_ws, float* __restrict__ num_ws)
{
    __shared__ int4 lds[2304];       // [0,2048): w2b swizzled; [2048,2304): w1p swizzled
    __shared__ float sred[4][256];   // per-wave den/num partials

    const int t = threadIdx.x;
    // stage w2b: 2048 16B units; unit s of row n stored at n*32 + (s ^ (n&7))
    const int4* w2b16 = (const int4*)w2b;
#pragma unroll
    for (int q = 0; q < 8; ++q) {
        const int i = t + q * 256;
        const int n = i >> 5, s = i & 31;
        lds[n * 32 + (s ^ (n & 7))] = w2b16[i];
    }
    // stage w1p: unit hid stored at 2048 + (hid ^ ((hid>>3)&3))
    lds[2048 + (t ^ ((t >> 3) & 3))] = ((const int4*)w1p)[t];
    __syncthreads();

    const int b    = blockIdx.y;
    const int pb   = blockIdx.x * 256;
    const int w    = t >> 6;
    const int lane = t & 63;
    const int l15  = lane & 15;
    const int lg   = lane >> 4;
    const int pwb  = pb + w * 64;

    const float* ip = img + (size_t)b * 3 * HW;

    // rgb for 4 pixel-groups (A-frag rows: px = pwb + s*16 + l15)
    float rr[4], gg[4], uu[4];
#pragma unroll
    for (int s = 0; s < 4; ++s) {
        const int px = pwb + s * 16 + l15;
        rr[s] = ip[px]; gg[s] = ip[HW + px]; uu[s] = ip[2 * HW + px];
    }

    f32x4 acc[4][4];
#pragma unroll
    for (int s = 0; s < 4; ++s)
#pragma unroll
        for (int ni = 0; ni < 4; ++ni)
            acc[s][ni] = (f32x4){0.f, 0.f, 0.f, 0.f};

#pragma unroll
    for (int c = 0; c < 8; ++c) {
        // A fragments: lane holds h[px][hid], hid = c*32 + lg*8 + j, for 4 px-groups
        bf16x8 a0, a1, a2, a3;
#pragma unroll
        for (int j = 0; j < 8; ++j) {
            const int hid = c * 32 + lg * 8 + j;
            const float4 wv = *(const float4*)&lds[2048 + (hid ^ lg)];
            float t0 = fmaf(rr[0], wv.x, fmaf(gg[0], wv.y, fmaf(uu[0], wv.z, wv.w)));
            float t1 = fmaf(rr[1], wv.x, fmaf(gg[1], wv.y, fmaf(uu[1], wv.z, wv.w)));
            float t2 = fmaf(rr[2], wv.x, fmaf(gg[2], wv.y, fmaf(uu[2], wv.z, wv.w)));
            float t3 = fmaf(rr[3], wv.x, fmaf(gg[3], wv.y, fmaf(uu[3], wv.z, wv.w)));
            a0[j] = f2bf(fmaxf(t0, 0.f));
            a1[j] = f2bf(fmaxf(t1, 0.f));
            a2[j] = f2bf(fmaxf(t2, 0.f));
            a3[j] = f2bf(fmaxf(t3, 0.f));
        }
        // B fragments from LDS (swizzled) + 16 MFMA
#pragma unroll
        for (int ni = 0; ni < 4; ++ni) {
            const int n = ni * 16 + l15;
            const bf16x8 bf = *(const bf16x8*)&lds[n * 32 + (((c * 4 + lg) ^ (n & 7)))];
            acc[0][ni] = __builtin_amdgcn_mfma_f32_16x16x32_bf16(a0, bf, acc[0][ni], 0, 0, 0);
            acc[1][ni] = __builtin_amdgcn_mfma_f32_16x16x32_bf16(a1, bf, acc[1][ni], 0, 0, 0);
            acc[2][ni] = __builtin_amdgcn_mfma_f32_16x16x32_bf16(a2, bf, acc[2][ni], 0, 0, 0);
            acc[3][ni] = __builtin_amdgcn_mfma_f32_16x16x32_bf16(a3, bf, acc[3][ni], 0, 0, 0);
        }
    }

    // Softmax over n=64 per pixel, WITHOUT max-subtraction (logits bounded, fp32 exp safe).
    // C layout: col(n)=ni*16+l15, row(px within group s)=lg*4+reg. Reduce over ni in-lane + l15 xor.
#pragma unroll
    for (int s = 0; s < 4; ++s) {
#pragma unroll
        for (int reg = 0; reg < 4; ++reg) {
            float v0 = __expf(acc[s][0][reg]);
            float v1 = __expf(acc[s][1][reg]);
            float v2 = __expf(acc[s][2][reg]);
            float v3 = __expf(acc[s][3][reg]);
            float sm = (v0 + v1) + (v2 + v3);
            sm += __shfl_xor(sm, 1);
            sm += __shfl_xor(sm, 2);
            sm += __shfl_xor(sm, 4);
            sm += __shfl_xor(sm, 8);
            const float inv = 1.f / sm;
            acc[s][0][reg] = v0 * inv; acc[s][1][reg] = v1 * inv;
            acc[s][2][reg] = v2 * inv; acc[s][3][reg] = v3 * inv;
        }
    }

    // ---- Fused den/num reduction (before any global stores, so the barrier is cheap) ----
    // Lane's pixels: px = pwb + s*16 + lg*4 + reg. JIT broadcast f32x4 img loads (low VGPR).
    float red[16];   // [q*4+ni], q: 0=den 1=numR 2=numG 3=numB
#pragma unroll
    for (int i = 0; i < 16; ++i) red[i] = 0.f;
#pragma unroll
    for (int s = 0; s < 4; ++s) {
        const int pxb = pwb + s * 16 + lg * 4;
        const f32x4 rC = *(const f32x4*)&ip[pxb];
        const f32x4 gC = *(const f32x4*)&ip[HW + pxb];
        const f32x4 uC = *(const f32x4*)&ip[2 * HW + pxb];
#pragma unroll
        for (int ni = 0; ni < 4; ++ni) {
#pragma unroll
            for (int reg = 0; reg < 4; ++reg) {
                const float mv = acc[s][ni][reg];
                red[ni]      += mv;
                red[4 + ni]   = fmaf(rC[reg], mv, red[4 + ni]);
                red[8 + ni]   = fmaf(gC[reg], mv, red[8 + ni]);
                red[12 + ni]  = fmaf(uC[reg], mv, red[12 + ni]);
            }
        }
    }
    // Reduce across the 4 lane-groups (lanes sharing l15): xor 16, 32.
#pragma unroll
    for (int i = 0; i < 16; ++i) {
        red[i] += __shfl_xor(red[i], 16);
        red[i] += __shfl_xor(red[i], 32);
    }
    if (lg == 0) {
#pragma unroll
        for (int ni = 0; ni < 4; ++ni) {
            const int n = ni * 16 + l15;
            sred[w][n]       = red[ni];
            sred[w][64 + n]  = red[4 + ni];
            sred[w][128 + n] = red[8 + ni];
            sred[w][192 + n] = red[12 + ni];
        }
    }
    __syncthreads();
    {
        const int q = t >> 6, n = t & 63;
        const float v = sred[0][t] + sred[1][t] + sred[2][t] + sred[3][t];
        if (q == 0) atomicAdd(&den_ws[b * K + n], v);
        else        atomicAdd(&num_ws[(b * 3 + (q - 1)) * K + n], v);
    }

    // Store m LAST: per (s,ni) the 4 regs are 4 consecutive px -> dwordx4; no barrier behind.
    float* mo = m_out + (size_t)b * K * HW + pwb;
#pragma unroll
    for (int s = 0; s < 4; ++s)
#pragma unroll
        for (int ni = 0; ni < 4; ++ni) {
            const int n = ni * 16 + l15;
            *(f32x4*)&mo[(size_t)n * HW + s * 16 + lg * 4] = acc[s][ni];
        }
}

// Kernel C: palette (fused) + transformed[b,c,p] = sum_k m[b,k,p] * palette[b,c,k].
// 4 px/thread, f32x4. Tile-0 blocks also write the palette output.
__global__ __launch_bounds__(256) void colorcnn_reconstruct(
    const float* __restrict__ m, const float* __restrict__ den_ws,
    const float* __restrict__ num_ws, float* __restrict__ pal_out,
    float* __restrict__ t_out)
{
    __shared__ float pl[192];
    const int b    = blockIdx.x / 49;
    const int tile = blockIdx.x % 49;
    const int t    = threadIdx.x;

    if (t < 192) {
        const int c = t >> 6, k = t & 63;
        const float v = num_ws[(b * 3 + c) * K + k] / (den_ws[b * K + k] + 1e-8f);
        pl[t] = v;
        if (tile == 0) pal_out[b * 3 * K + t] = v;
    }
    __syncthreads();

    const int p = tile * 1024 + t * 4;
    const float* mp = m + (size_t)b * K * HW + p;
    f32x4 ar = {0.f, 0.f, 0.f, 0.f}, ag = ar, ab = ar;
#pragma unroll
    for (int k = 0; k < K; ++k) {
        const f32x4 mv = *(const f32x4*)&mp[(size_t)k * HW];
        const float pr = pl[k], pg = pl[K + k], pu = pl[2 * K + k];
#pragma unroll
        for (int j = 0; j < 4; ++j) {
            ar[j] = fmaf(mv[j], pr, ar[j]);
            ag[j] = fmaf(mv[j], pg, ag[j]);
            ab[j] = fmaf(mv[j], pu, ab[j]);
        }
    }
    float* to = t_out + (size_t)b * 3 * HW + p;
    *(f32x4*)&to[0]      = ar;
    *(f32x4*)&to[HW]     = ag;
    *(f32x4*)&to[2 * HW] = ab;
}

extern "C" void kernel_launch(void* const* d_in, const int* in_sizes, int n_in,
                              void* d_out, int out_size, void* d_ws, size_t ws_size,
                              hipStream_t stream) {
    const float* img = (const float*)d_in[0];
    const float* W1  = (const float*)d_in[1];
    const float* b1  = (const float*)d_in[2];
    const float* W2  = (const float*)d_in[3];

    float* out   = (float*)d_out;
    float* t_out = out + OUT_T_OFF;
    float* m_out = out + OUT_M_OFF;
    float* p_out = out + OUT_P_OFF;

    float*  wsf    = (float*)d_ws;
    float*  den_ws = wsf + WS_DEN;
    float*  num_ws = wsf + WS_NUM;
    float4* w1p    = (float4*)(wsf + WS_W1P);
    ushort* w2b    = (ushort*)(wsf + WS_W2B);

    colorcnn_prep<<<8, 256, 0, stream>>>(W1, b1, W2, wsf, w1p, w2b);
    colorcnn_mlp_softmax<<<dim3(HW / 256, BATCH), 256, 0, stream>>>(img, w1p, w2b, m_out, den_ws, num_ws);
    colorcnn_reconstruct<<<BATCH * 49, 256, 0, stream>>>(m_out, den_ws, num_ws, p_out, t_out);
}